// Round 1
// baseline (6936.974 us; speedup 1.0000x reference)
//
#include <hip/hip_runtime.h>
#include <math.h>

// Problem constants (from reference)
#define NXD 64
#define NYD 48
#define NZD 32
#define NPT (NXD*NYD*NZD)   // 98304 points
#define PN  10              // neighbors per point
#define MF  5               // fourier modes
#define INF 33              // 3 + 2*5*3
#define H1  64
#define H2  32
#define H3  8

__device__ __forceinline__ float gelu_exact(float v) {
    // jax.nn.gelu(approximate=False): 0.5*x*(1+erf(x/sqrt(2)))
    return 0.5f * v * (1.0f + erff(v * 0.70710678118654752f));
}

// 2 threads per point; each handles 5 of the 10 neighbors, pair-reduced by shfl.
__global__ __launch_bounds__(256) void domino_mlp_kernel(
    const float* __restrict__ x,      // (NPT, PN, 3)
    const float* __restrict__ freqs,  // (MF,)
    const float* __restrict__ W1,     // (INF, H1)
    const float* __restrict__ b1,     // (H1,)
    const float* __restrict__ W2,     // (H1, H2)
    const float* __restrict__ b2,     // (H2,)
    const float* __restrict__ W3,     // (H2, H3)
    const float* __restrict__ b3,     // (H3,)
    float* __restrict__ out)          // (H3, NPT)
{
    const int t    = blockIdx.x * 256 + threadIdx.x;
    const int pt   = t >> 1;          // point index
    const int half = t & 1;           // which 5-neighbor half
    if (pt >= NPT) return;

    float fr[MF];
    #pragma unroll
    for (int m = 0; m < MF; ++m) fr[m] = freqs[m];

    float acc[H3];
    #pragma unroll
    for (int c = 0; c < H3; ++c) acc[c] = 0.0f;

    const int p0 = half * 5;
    #pragma unroll 1
    for (int pp = 0; pp < 5; ++pp) {
        const int p = p0 + pp;
        const float* xp = x + ((long)pt * PN + p) * 3;
        const float cx = xp[0], cy = xp[1], cz = xp[2];

        // ---- Fourier features: [x(3), sin(15), cos(15)] ; sin/cos index m*3+d
        float feat[INF];
        feat[0] = cx; feat[1] = cy; feat[2] = cz;
        #pragma unroll
        for (int m = 0; m < MF; ++m) {
            float s, c;
            __sincosf(cx * fr[m], &s, &c); feat[3 + m*3 + 0] = s; feat[18 + m*3 + 0] = c;
            __sincosf(cy * fr[m], &s, &c); feat[3 + m*3 + 1] = s; feat[18 + m*3 + 1] = c;
            __sincosf(cz * fr[m], &s, &c); feat[3 + m*3 + 2] = s; feat[18 + m*3 + 2] = c;
        }

        // ---- Layer 1: 33 -> 64, exact GELU
        float h1[H1];
        #pragma unroll
        for (int j = 0; j < H1; ++j) h1[j] = b1[j];
        #pragma unroll
        for (int i = 0; i < INF; ++i) {
            const float f = feat[i];
            #pragma unroll
            for (int j = 0; j < H1; ++j) h1[j] += f * W1[i*H1 + j];
        }
        #pragma unroll
        for (int j = 0; j < H1; ++j) h1[j] = gelu_exact(h1[j]);

        // ---- Layer 2: 64 -> 32, exact GELU
        float h2[H2];
        #pragma unroll
        for (int j = 0; j < H2; ++j) h2[j] = b2[j];
        #pragma unroll
        for (int i = 0; i < H1; ++i) {
            const float f = h1[i];
            #pragma unroll
            for (int j = 0; j < H2; ++j) h2[j] += f * W2[i*H2 + j];
        }
        #pragma unroll
        for (int j = 0; j < H2; ++j) h2[j] = gelu_exact(h2[j]);

        // ---- Layer 3: 32 -> 8, tanh; mask on |x-coord| > 1e-6
        const float mk = (fabsf(cx) > 1e-6f) ? 1.0f : 0.0f;
        #pragma unroll
        for (int c = 0; c < H3; ++c) {
            float a = b3[c];
            #pragma unroll
            for (int i = 0; i < H2; ++i) a += h2[i] * W3[i*H3 + c];
            acc[c] += mk * tanhf(a);
        }
    }

    // ---- pair reduction (threads 2k, 2k+1 are adjacent lanes in one wave)
    #pragma unroll
    for (int c = 0; c < H3; ++c) {
        acc[c] += __shfl_xor(acc[c], 1, 64);
    }
    if (half == 0) {
        #pragma unroll
        for (int c = 0; c < H3; ++c) out[(long)c * NPT + pt] = acc[c];
    }
}

extern "C" void kernel_launch(void* const* d_in, const int* in_sizes, int n_in,
                              void* d_out, int out_size, void* d_ws, size_t ws_size,
                              hipStream_t stream) {
    // setup_inputs order: x, grid(unused), freqs, W1, b1, W2, b2, W3, b3
    const float* x     = (const float*)d_in[0];
    const float* freqs = (const float*)d_in[2];
    const float* W1    = (const float*)d_in[3];
    const float* b1    = (const float*)d_in[4];
    const float* W2    = (const float*)d_in[5];
    const float* b2    = (const float*)d_in[6];
    const float* W3    = (const float*)d_in[7];
    const float* b3    = (const float*)d_in[8];
    float* out = (float*)d_out;

    const int threads = NPT * 2;           // 196608
    const int block   = 256;
    const int grid    = (threads + block - 1) / block;  // 768
    domino_mlp_kernel<<<grid, block, 0, stream>>>(x, freqs, W1, b1, W2, b2, W3, b3, out);
}